// Round 5
// baseline (711.599 us; speedup 1.0000x reference)
//
#include <hip/hip_runtime.h>
#include <hip/hip_bf16.h>
#include <stdint.h>

// ---- problem constants ----
#define D_MODEL  2048
#define N_INTER  1408
#define SH_INTER 2816
#define T_TOK    2048
#define NSLOT    (T_TOK * 4)

typedef __attribute__((ext_vector_type(8))) short bf16x8;
typedef __attribute__((ext_vector_type(4))) float f32x4;

__device__ __forceinline__ unsigned short f2bf(float f){
  unsigned int b = __builtin_bit_cast(unsigned int, f);
  b = (b + 0x7FFFu + ((b >> 16) & 1u)) >> 16;   // RNE, finite inputs
  return (unsigned short)b;
}
__device__ __forceinline__ unsigned short f2bfh(float f){   // hw cvt path (cvt_pk-able)
  __hip_bfloat16 h = __float2bfloat16(f);
  return __builtin_bit_cast(unsigned short, h);
}
__device__ __forceinline__ float bf2f(unsigned short h){
  unsigned int b = ((unsigned int)h) << 16;
  return __builtin_bit_cast(float, b);
}

// async global->LDS, 16B per lane; LDS dest = wave-uniform base + lane*16
#define GLOAD16(gp, lp) __builtin_amdgcn_global_load_lds( \
    (const __attribute__((address_space(1))) unsigned int*)(gp), \
    (__attribute__((address_space(3))) unsigned int*)(lp), 16, 0, 0)

// ---------------- fp32 -> bf16 convert (x only) ----------------
__global__ void cvt_bf16_kernel(const float* __restrict__ x,
                                unsigned short* __restrict__ o, int n4){
  const int stride = gridDim.x * blockDim.x;
  for (int i = blockIdx.x * blockDim.x + threadIdx.x; i < n4; i += stride){
    const float4 v = ((const float4*)x)[i];
    ushort4 u; u.x = f2bf(v.x); u.y = f2bf(v.y); u.z = f2bf(v.z); u.w = f2bf(v.w);
    ((ushort4*)o)[i] = u;
  }
}

// ---------------- gate: softmax + group-limited top-k ----------------
__global__ void gate_kernel(const float* __restrict__ x, const float* __restrict__ Wg,
                            int* __restrict__ cnt, int* __restrict__ list,
                            float* __restrict__ wslot){
  const int t = blockIdx.x;
  const int l = threadIdx.x;
  const int e = l & 15, q = l >> 4;
  const float* xr = x + (size_t)t * D_MODEL + q * 512;
  const float* wr = Wg + (size_t)e * D_MODEL + q * 512;
  float p = 0.f;
  #pragma unroll 4
  for (int i = 0; i < 512; i += 4){
    float4 xv = *(const float4*)(xr + i);
    float4 wv = *(const float4*)(wr + i);
    p += xv.x*wv.x + xv.y*wv.y + xv.z*wv.z + xv.w*wv.w;
  }
  p += __shfl_xor(p, 16);
  p += __shfl_xor(p, 32);
  float mx = p;
  for (int d = 1; d < 16; d <<= 1) mx = fmaxf(mx, __shfl_xor(mx, d));
  float ex = __expf(p - mx);
  float sum = ex;
  for (int d = 1; d < 16; d <<= 1) sum += __shfl_xor(sum, d);
  const float sc = ex / sum;
  float gm = fmaxf(sc, __shfl_xor(sc, 1));
  gm = fmaxf(gm, __shfl_xor(gm, 2));
  const float g0 = __shfl(gm, 0), g1 = __shfl(gm, 4),
              g2 = __shfl(gm, 8), g3 = __shfl(gm, 12);
  const int grp = e >> 2;
  const float gs[4] = {g0, g1, g2, g3};
  int grank = 0;
  #pragma unroll
  for (int j = 0; j < 4; ++j)
    if (gs[j] > gm || (gs[j] == gm && j < grp)) grank++;
  const float msc = (grank < 2) ? sc : -INFINITY;
  int erank = 0;
  #pragma unroll
  for (int j = 0; j < 16; ++j){
    const float oj = __shfl(msc, j);
    if (oj > msc || (oj == msc && j < e)) erank++;
  }
  if (q == 0 && erank < 4 && msc > -INFINITY){
    const int pos = atomicAdd(&cnt[e], 1);
    const int slot = (t << 2) | erank;
    list[e * T_TOK + pos] = slot;
    wslot[slot] = sc;            // ROUTE_SCALE = 1
  }
}

// ---- GEMM: A bf16 (LDS-staged), B fp32 DIRECT (LDS-staged, cvt on read) ----
// BM=128 BN=128 BK=32, 4 waves (2x2 of 64x64). Both operands via double-buffered
// global_load_lds with pre-swizzled source + XOR read (conflict-free, derived).
// MODE 0: linear A, bf16 out at grow     MODE 1: linear A, fp32 out (+ ks panel)
// MODE 2: gather A by token (entry>>2), bf16 out at slot
// MODE 3: gather A by slot (entry),     bf16 out at slot
// NTH > 0: dual-source B (panel nt<NTH from B1, else B3) -- G/U concat along N.
template<int MODE, int NTH, int KSPLIT>
__global__ __launch_bounds__(256, 3)
void gemm5_kernel(const unsigned short* __restrict__ A,
                  const float* __restrict__ B1,
                  const float* __restrict__ B3,
                  void* __restrict__ OutP,
                  const int* __restrict__ list,
                  const int* __restrict__ cnt,
                  int N, int K, int MT, int NTtot, size_t eStride)
{
  constexpr bool GATHER = (MODE >= 2);
  __shared__ unsigned short As[2 * 128 * 32];   // 16 KB
  __shared__ float          Bs[2 * 128 * 32];   // 32 KB

  // bijective XCD-chunked swizzle (all grids % 8 == 0)
  const int per = gridDim.x >> 3;
  const int gsw = (blockIdx.x & 7) * per + (blockIdx.x >> 3);
  const int mt = gsw % MT;
  int r1 = gsw / MT;
  int ks = 0;
  if constexpr (KSPLIT > 1){ ks = r1 % KSPLIT; r1 /= KSPLIT; }
  const int nt = GATHER ? (r1 % NTtot) : r1;
  const int e  = GATHER ? (r1 / NTtot) : 0;

  const int cntE = GATHER ? cnt[e] : (MT * 128);
  if (mt * 128 >= cntE) return;

  // B source select (block-uniform)
  const float* Bsel; int ntb;
  if constexpr (NTH > 0){
    if (nt >= NTH){ Bsel = B3; ntb = nt - NTH; } else { Bsel = B1; ntb = nt; }
  } else { Bsel = B1; ntb = nt; }
  if constexpr (GATHER) Bsel += (size_t)e * eStride;

  const int tid = threadIdx.x, wid = tid >> 6, lane = tid & 63;
  const int kOff = ks * (K / KSPLIT);           // element offset of this K-split

  // ---- A staging: wave w rows [32w,32w+32), 2 insts x 16 rows ----
  const int rt0 = 32 * wid + (lane >> 2), rt1 = rt0 + 16;
  const int sxA = ((lane & 3) ^ ((lane >> 3) & 3)) << 3;   // shorts (src slot)
  int ar0, ar1;
  if constexpr (GATHER){
    const int lim = cntE - 1;
    int p0 = mt * 128 + rt0; p0 = p0 < lim ? p0 : lim;
    int p1 = mt * 128 + rt1; p1 = p1 < lim ? p1 : lim;
    const int e0 = list[e * T_TOK + p0], e1 = list[e * T_TOK + p1];
    ar0 = (MODE == 2) ? (e0 >> 2) : e0;
    ar1 = (MODE == 2) ? (e1 >> 2) : e1;
  } else { ar0 = mt * 128 + rt0; ar1 = mt * 128 + rt1; }
  const unsigned short* pa0 = A + (size_t)ar0 * K + kOff + sxA;
  const unsigned short* pa1 = A + (size_t)ar1 * K + kOff + sxA;
  const int aW0 = (32 * wid) * 32, aW1 = aW0 + 16 * 32;    // shorts
  const int aStride = 128 * 32;

  // ---- B staging (fp32): wave w rows [32w,32w+32), 4 insts x 8 rows ----
  const int brt = 32 * wid + (lane >> 3);                   // row for inst j=0
  const int sxB = ((lane & 7) ^ ((lane >> 3) & 7)) << 2;    // floats (src slot*4)
  const float* pb0 = Bsel + (size_t)(ntb * 128 + brt     ) * K + kOff + sxB;
  const float* pb1 = Bsel + (size_t)(ntb * 128 + brt +  8) * K + kOff + sxB;
  const float* pb2 = Bsel + (size_t)(ntb * 128 + brt + 16) * K + kOff + sxB;
  const float* pb3 = Bsel + (size_t)(ntb * 128 + brt + 24) * K + kOff + sxB;
  const int bW0 = wid * 1024, bW1 = bW0 + 256, bW2 = bW0 + 512, bW3 = bW0 + 768; // floats
  const int bStride = 128 * 32;

  // ---- fragment read offsets ----
  const int wr = wid >> 1, wc = wid & 1, lr = lane & 15, lq = lane >> 4;
  const int fxA = ((lq ^ ((lr >> 1) & 3)) << 3);            // shorts
  int aoff[4], boff0[4], boff1[4];
  #pragma unroll
  for (int m = 0; m < 4; ++m) aoff[m] = (wr * 64 + m * 16 + lr) * 32 + fxA;
  #pragma unroll
  for (int n = 0; n < 4; ++n){
    const int rowB = wc * 64 + n * 16 + lr;
    const int ph0 = (2 * lq) ^ (lr & 7);                    // 16B slot (of 8)
    boff0[n] = rowB * 32 + ph0 * 4;                         // floats
    boff1[n] = rowB * 32 + (ph0 ^ 1) * 4;
  }

  f32x4 acc[4][4];
  const f32x4 zero = {0.f, 0.f, 0.f, 0.f};
  #pragma unroll
  for (int m = 0; m < 4; ++m)
    #pragma unroll
    for (int n = 0; n < 4; ++n) acc[m][n] = zero;

  const int KTL = (K >> 5) / KSPLIT;
  // prologue: stage step 0 into buffer 0
  GLOAD16(pa0, As + aW0);
  GLOAD16(pa1, As + aW1);
  GLOAD16(pb0, Bs + bW0);
  GLOAD16(pb1, Bs + bW1);
  GLOAD16(pb2, Bs + bW2);
  GLOAD16(pb3, Bs + bW3);
  pa0 += 32; pa1 += 32; pb0 += 32; pb1 += 32; pb2 += 32; pb3 += 32;
  int cur = 0;

  for (int kt = 0; kt < KTL; ++kt){
    __syncthreads();                 // buf[cur] staged; prev LDS reads done
    if (kt + 1 < KTL){               // prefetch next tile under the MFMA phase
      const int nx = cur ^ 1;
      GLOAD16(pa0, As + nx * aStride + aW0);
      GLOAD16(pa1, As + nx * aStride + aW1);
      GLOAD16(pb0, Bs + nx * bStride + bW0);
      GLOAD16(pb1, Bs + nx * bStride + bW1);
      GLOAD16(pb2, Bs + nx * bStride + bW2);
      GLOAD16(pb3, Bs + nx * bStride + bW3);
      pa0 += 32; pa1 += 32; pb0 += 32; pb1 += 32; pb2 += 32; pb3 += 32;
    }
    const unsigned short* aC = As + cur * aStride;
    const float* bC = Bs + cur * bStride;
    bf16x8 af[4];
    #pragma unroll
    for (int m = 0; m < 4; ++m) af[m] = *(const bf16x8*)(aC + aoff[m]);
    #pragma unroll
    for (int n = 0; n < 4; ++n){
      const f32x4 v0 = *(const f32x4*)(bC + boff0[n]);
      const f32x4 v1 = *(const f32x4*)(bC + boff1[n]);
      bf16x8 bfr;
      bfr[0] = (short)f2bfh(v0[0]); bfr[1] = (short)f2bfh(v0[1]);
      bfr[2] = (short)f2bfh(v0[2]); bfr[3] = (short)f2bfh(v0[3]);
      bfr[4] = (short)f2bfh(v1[0]); bfr[5] = (short)f2bfh(v1[1]);
      bfr[6] = (short)f2bfh(v1[2]); bfr[7] = (short)f2bfh(v1[3]);
      #pragma unroll
      for (int m = 0; m < 4; ++m)
        acc[m][n] = __builtin_amdgcn_mfma_f32_16x16x32_bf16(af[m], bfr, acc[m][n], 0, 0, 0);
    }
    cur ^= 1;
  }

  // ---- epilogue: C/D col = lane&15, row = (lane>>4)*4 + reg ----
  const int colBase = nt * 128 + wc * 64;
  #pragma unroll
  for (int m = 0; m < 4; ++m){
    #pragma unroll
    for (int r = 0; r < 4; ++r){
      const int grow = mt * 128 + wr * 64 + m * 16 + lq * 4 + r;
      if constexpr (MODE == 1){
        float* op = (float*)OutP + (size_t)ks * MT * 128 * N + (size_t)grow * N + colBase;
        #pragma unroll
        for (int n = 0; n < 4; ++n) op[n * 16 + lr] = acc[m][n][r];
      } else if constexpr (MODE == 0){
        unsigned short* op = (unsigned short*)OutP + (size_t)grow * N + colBase;
        #pragma unroll
        for (int n = 0; n < 4; ++n) op[n * 16 + lr] = f2bf(acc[m][n][r]);
      } else {
        if (grow >= cntE) continue;
        const int orow = list[e * T_TOK + grow];    // slot
        unsigned short* op = (unsigned short*)OutP + (size_t)orow * N + colBase;
        #pragma unroll
        for (int n = 0; n < 4; ++n) op[n * 16 + lr] = f2bf(acc[m][n][r]);
      }
    }
  }
}

// ---- SwiGLU on N-concat layout: H[r][i] = silu(GU[r][i]) * GU[r][NI+i] ----
__global__ void swiglu_split_kernel(const unsigned short* __restrict__ GU,
                                    unsigned short* __restrict__ H,
                                    int n8, int NI8){
  const int stride = gridDim.x * blockDim.x;
  for (int i = blockIdx.x * blockDim.x + threadIdx.x; i < n8; i += stride){
    const int r = i / NI8, c = i - r * NI8;
    const bf16x8 g = ((const bf16x8*)GU)[(size_t)r * 2 * NI8 + c];
    const bf16x8 u = ((const bf16x8*)GU)[(size_t)r * 2 * NI8 + NI8 + c];
    bf16x8 h;
    #pragma unroll
    for (int j = 0; j < 8; ++j){
      const float gv = bf2f((unsigned short)g[j]);
      const float uv = bf2f((unsigned short)u[j]);
      h[j] = (short)f2bf(gv / (1.f + __expf(-gv)) * uv);
    }
    ((bf16x8*)H)[i] = h;
  }
}

// ---- combine: out[t] = P0[t] + P1[t] + sum_k wslot[4t+k] * H2[4t+k] ----
__global__ void combine_kernel(const unsigned short* __restrict__ H2,
                               const float* __restrict__ P,
                               const float* __restrict__ wslot,
                               float* __restrict__ out){
  const int t = blockIdx.x;
  const int c = threadIdx.x * 8;
  float w[4];
  #pragma unroll
  for (int k = 0; k < 4; ++k) w[k] = wslot[t * 4 + k];
  const float* p0 = P + (size_t)t * D_MODEL + c;
  const float* p1 = P + (size_t)(T_TOK + t) * D_MODEL + c;
  float a[8];
  #pragma unroll
  for (int j = 0; j < 8; ++j) a[j] = p0[j] + p1[j];
  #pragma unroll
  for (int k = 0; k < 4; ++k){
    const bf16x8 hv = *(const bf16x8*)(H2 + (size_t)(t * 4 + k) * D_MODEL + c);
    #pragma unroll
    for (int j = 0; j < 8; ++j) a[j] += w[k] * bf2f((unsigned short)hv[j]);
  }
  float* o = out + (size_t)t * D_MODEL + c;
  #pragma unroll
  for (int j = 0; j < 8; ++j) o[j] = a[j];
}

extern "C" void kernel_launch(void* const* d_in, const int* in_sizes, int n_in,
                              void* d_out, int out_size, void* d_ws, size_t ws_size,
                              hipStream_t stream)
{
  const float* x   = (const float*)d_in[0];
  const float* Wg  = (const float*)d_in[1];
  const float* W1  = (const float*)d_in[2];
  const float* W3  = (const float*)d_in[3];
  const float* W2  = (const float*)d_in[4];
  const float* Ws1 = (const float*)d_in[5];
  const float* Ws3 = (const float*)d_in[6];
  const float* Ws2 = (const float*)d_in[7];
  float* out = (float*)d_out;

  // ---- workspace layout (phase-reused; max touched = 150.6 MiB) ----
  char* ws = (char*)d_ws;
  int*   cnt   = (int*)(ws);                     // 64 B
  int*   list  = (int*)(ws + 4096);              // 128 KiB
  float* wslot = (float*)(ws + 4096 + 131072);   // 32 KiB
  unsigned short* xbf  = (unsigned short*)(ws + ((size_t)1   << 20)); // 8.4 MB
  unsigned short* GU_s = (unsigned short*)(ws + ((size_t)10  << 20)); // 23.1 MB (dead after swiglu_s)
  unsigned short* Hs   = (unsigned short*)(ws + ((size_t)34  << 20)); // 11.5 MB (dead after sharedDown)
  unsigned short* GU_r = (unsigned short*)(ws + ((size_t)46  << 20)); // 46.1 MB (dead after swiglu_r)
  unsigned short* Hc   = (unsigned short*)(ws + ((size_t)93  << 20)); // 23.1 MB (dead after routedDown)
  unsigned short* H2   = (unsigned short*)(ws + ((size_t)10  << 20)); // 33.6 MB (over GU_s+Hs, both dead)
  float*          P    = (float*)        (ws + ((size_t)117 << 20));  // 33.6 MB (2 K-split partials)

  hipMemsetAsync(cnt, 0, 4096, stream);
  cvt_bf16_kernel<<<2048, 256, 0, stream>>>(x, xbf, T_TOK * D_MODEL / 4);
  gate_kernel<<<T_TOK, 64, 0, stream>>>(x, Wg, cnt, list, wslot);

  // shared G+U (N-concat):  M=2048, N=5632, K=2048, grid 16x44=704
  gemm5_kernel<0, 22, 1><<<16 * 44, 256, 0, stream>>>(
      xbf, Ws1, Ws3, GU_s, nullptr, nullptr, 2 * SH_INTER, D_MODEL, 16, 44, 0);
  swiglu_split_kernel<<<2048, 256, 0, stream>>>(GU_s, Hs, T_TOK * SH_INTER / 8, SH_INTER / 8);

  // shared down (K-split x2 -> fp32 partials): M=2048, N=2048, K=2816, grid 16x16x2=512
  gemm5_kernel<1, 0, 2><<<16 * 16 * 2, 256, 0, stream>>>(
      Hs, Ws2, nullptr, P, nullptr, nullptr, D_MODEL, SH_INTER, 16, 16, 0);

  // routed G+U (N-concat, per-expert): N=2816, K=2048, grid 16x22x16=5632
  gemm5_kernel<2, 11, 1><<<16 * 22 * 16, 256, 0, stream>>>(
      xbf, W1, W3, GU_r, list, cnt, 2 * N_INTER, D_MODEL, 16, 22,
      (size_t)N_INTER * D_MODEL);
  swiglu_split_kernel<<<2048, 256, 0, stream>>>(GU_r, Hc, NSLOT * N_INTER / 8, N_INTER / 8);

  // routed down: N=2048, K=1408, grid 16x16x16=4096
  gemm5_kernel<3, 0, 1><<<16 * 16 * 16, 256, 0, stream>>>(
      Hc, W2, nullptr, H2, list, cnt, D_MODEL, N_INTER, 16, 16,
      (size_t)D_MODEL * N_INTER);

  combine_kernel<<<T_TOK, 256, 0, stream>>>(H2, P, wslot, out);
}

// Round 6
// 604.529 us; speedup vs baseline: 1.1771x; 1.1771x over previous
//
#include <hip/hip_runtime.h>
#include <stdint.h>

// ---- problem constants ----
#define D_MODEL  2048
#define N_INTER  1408
#define SH_INTER 2816
#define T_TOK    2048
#define NSLOT    (T_TOK * 4)
#define MIB(x)   ((size_t)(x) << 20)

typedef __attribute__((ext_vector_type(8))) short bf16x8;
typedef __attribute__((ext_vector_type(4))) float f32x4;

__device__ __forceinline__ unsigned short f2bf(float f){
  unsigned int b = __builtin_bit_cast(unsigned int, f);
  b = (b + 0x7FFFu + ((b >> 16) & 1u)) >> 16;   // RNE, finite inputs
  return (unsigned short)b;
}
__device__ __forceinline__ float bf2f(unsigned short h){
  unsigned int b = ((unsigned int)h) << 16;
  return __builtin_bit_cast(float, b);
}

// async global->LDS, 16B per lane; LDS dest = wave-uniform base + lane*16
#define GLOAD16(gp, lp) __builtin_amdgcn_global_load_lds( \
    (const __attribute__((address_space(1))) unsigned int*)(gp), \
    (__attribute__((address_space(3))) unsigned int*)(lp), 16, 0, 0)

// ---------------- fp32 -> bf16 streaming convert ----------------
__global__ void cvt_bf16_kernel(const float* __restrict__ x,
                                unsigned short* __restrict__ o, int n4){
  const int stride = gridDim.x * blockDim.x;
  for (int i = blockIdx.x * blockDim.x + threadIdx.x; i < n4; i += stride){
    const float4 v = ((const float4*)x)[i];
    ushort4 u; u.x = f2bf(v.x); u.y = f2bf(v.y); u.z = f2bf(v.z); u.w = f2bf(v.w);
    ((ushort4*)o)[i] = u;
  }
}

// ---------------- gate: softmax + group-limited top-k ----------------
__global__ void gate_kernel(const float* __restrict__ x, const float* __restrict__ Wg,
                            int* __restrict__ cnt, int* __restrict__ list,
                            float* __restrict__ wslot){
  const int t = blockIdx.x;
  const int l = threadIdx.x;
  const int e = l & 15, q = l >> 4;
  const float* xr = x + (size_t)t * D_MODEL + q * 512;
  const float* wr = Wg + (size_t)e * D_MODEL + q * 512;
  float p = 0.f;
  #pragma unroll 4
  for (int i = 0; i < 512; i += 4){
    float4 xv = *(const float4*)(xr + i);
    float4 wv = *(const float4*)(wr + i);
    p += xv.x*wv.x + xv.y*wv.y + xv.z*wv.z + xv.w*wv.w;
  }
  p += __shfl_xor(p, 16);
  p += __shfl_xor(p, 32);
  float mx = p;
  for (int d = 1; d < 16; d <<= 1) mx = fmaxf(mx, __shfl_xor(mx, d));
  float ex = __expf(p - mx);
  float sum = ex;
  for (int d = 1; d < 16; d <<= 1) sum += __shfl_xor(sum, d);
  const float sc = ex / sum;
  float gm = fmaxf(sc, __shfl_xor(sc, 1));
  gm = fmaxf(gm, __shfl_xor(gm, 2));
  const float g0 = __shfl(gm, 0), g1 = __shfl(gm, 4),
              g2 = __shfl(gm, 8), g3 = __shfl(gm, 12);
  const int grp = e >> 2;
  const float gs[4] = {g0, g1, g2, g3};
  int grank = 0;
  #pragma unroll
  for (int j = 0; j < 4; ++j)
    if (gs[j] > gm || (gs[j] == gm && j < grp)) grank++;
  const float msc = (grank < 2) ? sc : -INFINITY;
  int erank = 0;
  #pragma unroll
  for (int j = 0; j < 16; ++j){
    const float oj = __shfl(msc, j);
    if (oj > msc || (oj == msc && j < e)) erank++;
  }
  if (q == 0 && erank < 4 && msc > -INFINITY){
    const int pos = atomicAdd(&cnt[e], 1);
    const int slot = (t << 2) | erank;
    list[e * T_TOK + pos] = slot;
    wslot[slot] = sc;            // ROUTE_SCALE = 1
  }
}

// ---- GEMM: BM=128 BN=128 BK=32, 4 waves (2x2 of 64x64), bf16 A and B ----
// 3-deep pipeline: 3 LDS buffers, counted s_waitcnt vmcnt(8) (T4) -- never a
// full drain in steady state. Both operands via global_load_lds width-16 with
// pre-swizzled source + XOR read (R4-verified conflict-free).
// MODE 0: linear A, bf16 out     MODE 1: linear A, fp32 out
// MODE 2: gather A by token (entry>>2), bf16 out at slot
// MODE 3: gather A by slot (entry),     bf16 out at slot
template<int MODE>
__global__ __launch_bounds__(256, 3)
void gemm6_kernel(const unsigned short* __restrict__ A,
                  const unsigned short* __restrict__ B,
                  void* __restrict__ OutP,
                  const int* __restrict__ list,
                  const int* __restrict__ cnt,
                  int N, int K, int Astride, int MT, int NT)
{
  constexpr bool GATHER = (MODE >= 2);
  __shared__ unsigned short As[3 * 128 * 32];   // 24 KB
  __shared__ unsigned short Bs[3 * 128 * 32];   // 24 KB

  // bijective XCD-chunked swizzle (all grids % 8 == 0)
  const int per = gridDim.x >> 3;
  const int gsw = (blockIdx.x & 7) * per + (blockIdx.x >> 3);
  const int mt   = gsw % MT;
  const int rest = gsw / MT;
  const int nt = GATHER ? (rest % NT) : rest;
  const int e  = GATHER ? (rest / NT) : 0;

  const int cntE = GATHER ? cnt[e] : (MT * 128);
  if (mt * 128 >= cntE) return;

  const int tid = threadIdx.x, wid = tid >> 6, lane = tid & 63;

  // wave w stages tile rows [32w,32w+32) as 2 insts x 16 rows;
  // lane -> row += lane>>2, phys 16B-slot = lane&3, src slot = phys ^ ((row>>1)&3)
  const int rt0 = 32 * wid + (lane >> 2), rt1 = rt0 + 16;
  const int sxA = ((lane & 3) ^ ((lane >> 3) & 3)) << 3;   // shorts

  int ar0, ar1;
  if constexpr (GATHER){
    const int lim = cntE - 1;
    int p0 = mt * 128 + rt0; p0 = p0 < lim ? p0 : lim;
    int p1 = mt * 128 + rt1; p1 = p1 < lim ? p1 : lim;
    const int e0 = list[e * T_TOK + p0], e1 = list[e * T_TOK + p1];
    ar0 = (MODE == 2) ? (e0 >> 2) : e0;
    ar1 = (MODE == 2) ? (e1 >> 2) : e1;
  } else { ar0 = mt * 128 + rt0; ar1 = mt * 128 + rt1; }

  const unsigned short* pa0 = A + (size_t)ar0 * Astride + sxA;
  const unsigned short* pa1 = A + (size_t)ar1 * Astride + sxA;
  const unsigned short* pb0 = B + (GATHER ? (size_t)e * N * K : 0)
                            + (size_t)(nt * 128 + rt0) * K + sxA;
  const unsigned short* pb1 = pb0 + (size_t)16 * K;

  const int aW0 = (32 * wid) * 32, aW1 = aW0 + 16 * 32;    // shorts
  const int bufStride = 128 * 32;

  // fragment read offsets (XOR-swizzled, phys slot = lq ^ ((row>>1)&3))
  const int wr = wid >> 1, wc = wid & 1, lr = lane & 15, lq = lane >> 4;
  const int fx = ((lq ^ ((lr >> 1) & 3)) << 3);
  int aoff[4], boff[4];
  #pragma unroll
  for (int m = 0; m < 4; ++m) aoff[m] = (wr * 64 + m * 16 + lr) * 32 + fx;
  #pragma unroll
  for (int n = 0; n < 4; ++n) boff[n] = (wc * 64 + n * 16 + lr) * 32 + fx;

  f32x4 acc[4][4];
  const f32x4 zero = {0.f, 0.f, 0.f, 0.f};
  #pragma unroll
  for (int m = 0; m < 4; ++m)
    #pragma unroll
    for (int n = 0; n < 4; ++n) acc[m][n] = zero;

  const int KT = K >> 5;                     // >= 44 in all uses
  // prologue: stage tiles 0,1,2 into buffers 0,1,2
  #pragma unroll
  for (int t = 0; t < 3; ++t){
    GLOAD16(pa0, As + t * bufStride + aW0);
    GLOAD16(pa1, As + t * bufStride + aW1);
    GLOAD16(pb0, Bs + t * bufStride + aW0);
    GLOAD16(pb1, Bs + t * bufStride + aW1);
    pa0 += 32; pa1 += 32; pb0 += 32; pb1 += 32;
  }
  int c = 0;

  for (int kt = 0; kt < KT; ++kt){
    // tile kt landed when <= (tiles in flight)*4 outstanding (T4: counted, not 0)
    if (kt < KT - 2)       asm volatile("s_waitcnt vmcnt(8)" ::: "memory");
    else if (kt == KT - 2) asm volatile("s_waitcnt vmcnt(4)" ::: "memory");
    else                   asm volatile("s_waitcnt vmcnt(0)" ::: "memory");
    __builtin_amdgcn_s_barrier();            // tile kt visible to all waves

    const unsigned short* aC = As + c * bufStride;
    const unsigned short* bC = Bs + c * bufStride;
    bf16x8 af[4], bf[4];
    #pragma unroll
    for (int m = 0; m < 4; ++m) af[m] = *(const bf16x8*)(aC + aoff[m]);
    #pragma unroll
    for (int n = 0; n < 4; ++n) bf[n] = *(const bf16x8*)(bC + boff[n]);

    asm volatile("s_waitcnt lgkmcnt(0)" ::: "memory");  // my reads complete
    __builtin_amdgcn_sched_barrier(0);                  // rule #18
    __builtin_amdgcn_s_barrier();            // all waves done reading buf c

    if (kt + 3 < KT){                        // refill buf c with tile kt+3
      GLOAD16(pa0, As + c * bufStride + aW0);
      GLOAD16(pa1, As + c * bufStride + aW1);
      GLOAD16(pb0, Bs + c * bufStride + aW0);
      GLOAD16(pb1, Bs + c * bufStride + aW1);
      pa0 += 32; pa1 += 32; pb0 += 32; pb1 += 32;
    }

    #pragma unroll
    for (int n = 0; n < 4; ++n)
      #pragma unroll
      for (int m = 0; m < 4; ++m)
        acc[m][n] = __builtin_amdgcn_mfma_f32_16x16x32_bf16(af[m], bf[n], acc[m][n], 0, 0, 0);

    c = (c == 2) ? 0 : c + 1;
  }

  // ---- epilogue: C/D col = lane&15, row = (lane>>4)*4 + reg ----
  const int colBase = nt * 128 + wc * 64;
  #pragma unroll
  for (int m = 0; m < 4; ++m){
    #pragma unroll
    for (int r = 0; r < 4; ++r){
      const int grow = mt * 128 + wr * 64 + m * 16 + lq * 4 + r;
      if constexpr (MODE == 1){
        float* op = (float*)OutP + (size_t)grow * N + colBase;
        #pragma unroll
        for (int n = 0; n < 4; ++n) op[n * 16 + lr] = acc[m][n][r];
      } else if constexpr (MODE == 0){
        unsigned short* op = (unsigned short*)OutP + (size_t)grow * N + colBase;
        #pragma unroll
        for (int n = 0; n < 4; ++n) op[n * 16 + lr] = f2bf(acc[m][n][r]);
      } else {
        if (grow >= cntE) continue;
        const int orow = list[e * T_TOK + grow];    // slot
        unsigned short* op = (unsigned short*)OutP + (size_t)orow * N + colBase;
        #pragma unroll
        for (int n = 0; n < 4; ++n) op[n * 16 + lr] = f2bf(acc[m][n][r]);
      }
    }
  }
}

// ---- SwiGLU in place on N-concat rows: GU[r][c] = silu(GU[r][c])*GU[r][NI+c] ----
__global__ void swiglu_ip_kernel(unsigned short* __restrict__ GU, int n8, int NI8){
  const int stride = gridDim.x * blockDim.x;
  bf16x8* p = (bf16x8*)GU;
  for (int i = blockIdx.x * blockDim.x + threadIdx.x; i < n8; i += stride){
    const int r = i / NI8, ccol = i - r * NI8;
    const size_t gi = (size_t)r * 2 * NI8 + ccol;
    const bf16x8 g = p[gi];
    const bf16x8 u = p[gi + NI8];
    bf16x8 h;
    #pragma unroll
    for (int j = 0; j < 8; ++j){
      const float gv = bf2f((unsigned short)g[j]);
      const float uv = bf2f((unsigned short)u[j]);
      h[j] = (short)f2bf(gv / (1.f + __expf(-gv)) * uv);
    }
    p[gi] = h;
  }
}

// ---- SwiGLU, separate buffers, in place into G ----
__global__ void swiglu2_kernel(unsigned short* __restrict__ G,
                               const unsigned short* __restrict__ U, int n8){
  const int stride = gridDim.x * blockDim.x;
  for (int i = blockIdx.x * blockDim.x + threadIdx.x; i < n8; i += stride){
    const bf16x8 g = ((const bf16x8*)G)[i];
    const bf16x8 u = ((const bf16x8*)U)[i];
    bf16x8 h;
    #pragma unroll
    for (int j = 0; j < 8; ++j){
      const float gv = bf2f((unsigned short)g[j]);
      const float uv = bf2f((unsigned short)u[j]);
      h[j] = (short)f2bf(gv / (1.f + __expf(-gv)) * uv);
    }
    ((bf16x8*)G)[i] = h;
  }
}

// ---- combine: out[t] += sum_k wslot[4t+k] * H2[4t+k] ----
__global__ void combine_kernel(const unsigned short* __restrict__ H2,
                               const float* __restrict__ wslot,
                               float* __restrict__ out){
  const int t = blockIdx.x;
  const int ccol = threadIdx.x * 8;
  float w[4];
  #pragma unroll
  for (int k = 0; k < 4; ++k) w[k] = wslot[t * 4 + k];
  float* o = out + (size_t)t * D_MODEL + ccol;
  float a[8];
  #pragma unroll
  for (int j = 0; j < 8; ++j) a[j] = o[j];
  #pragma unroll
  for (int k = 0; k < 4; ++k){
    const bf16x8 hv = *(const bf16x8*)(H2 + (size_t)(t * 4 + k) * D_MODEL + ccol);
    #pragma unroll
    for (int j = 0; j < 8; ++j) a[j] += w[k] * bf2f((unsigned short)hv[j]);
  }
  #pragma unroll
  for (int j = 0; j < 8; ++j) o[j] = a[j];
}

extern "C" void kernel_launch(void* const* d_in, const int* in_sizes, int n_in,
                              void* d_out, int out_size, void* d_ws, size_t ws_size,
                              hipStream_t stream)
{
  const float* x   = (const float*)d_in[0];
  const float* Wg  = (const float*)d_in[1];
  const float* W1  = (const float*)d_in[2];
  const float* W3  = (const float*)d_in[3];
  const float* W2  = (const float*)d_in[4];
  const float* Ws1 = (const float*)d_in[5];
  const float* Ws3 = (const float*)d_in[6];
  const float* Ws2 = (const float*)d_in[7];
  float* out = (float*)d_out;

  // ---- phase-reused workspace (max touched = 143 MiB; R4 proved 145) ----
  char* ws = (char*)d_ws;
  int*   cnt   = (int*)(ws);                     // 64 B
  int*   list  = (int*)(ws + 4096);              // 128 KiB
  float* wslot = (float*)(ws + 4096 + 131072);   // 32 KiB
  unsigned short* xbf  = (unsigned short*)(ws + MIB(1));    // 8 MiB  [dies before H2]
  unsigned short* H2   = (unsigned short*)(ws + MIB(1));    // 32 MiB [routed down out]
  unsigned short* GU_s = (unsigned short*)(ws + MIB(9));    // 22 MiB [dies after shared down]
  unsigned short* Ubuf = (unsigned short*)(ws + MIB(9));    // 22 MiB [dies after swiglu2]
  unsigned short* Wb   = (unsigned short*)(ws + MIB(33));   // <=88 MiB [current bf16 weight]
  unsigned short* Gbuf = (unsigned short*)(ws + MIB(121));  // 22 MiB [G out -> H in place]
  unsigned short* Wb2  = Wb + (size_t)SH_INTER * D_MODEL;   // second shared slot

  hipMemsetAsync(cnt, 0, 4096, stream);
  cvt_bf16_kernel<<<2048, 256, 0, stream>>>(x, xbf, T_TOK * D_MODEL / 4);
  gate_kernel<<<T_TOK, 64, 0, stream>>>(x, Wg, cnt, list, wslot);

  // ---- shared expert ----
  cvt_bf16_kernel<<<4096, 256, 0, stream>>>(Ws1, Wb,  SH_INTER * D_MODEL / 4);
  cvt_bf16_kernel<<<4096, 256, 0, stream>>>(Ws3, Wb2, SH_INTER * D_MODEL / 4);
  // G+U concat: M=2048, N=5632, K=2048, grid 16x44=704
  gemm6_kernel<0><<<16 * 44, 256, 0, stream>>>(xbf, Wb, GU_s, nullptr, nullptr,
                                               2 * SH_INTER, D_MODEL, D_MODEL, 16, 44);
  swiglu_ip_kernel<<<2048, 256, 0, stream>>>(GU_s, T_TOK * SH_INTER / 8, SH_INTER / 8);
  cvt_bf16_kernel<<<4096, 256, 0, stream>>>(Ws2, Wb, D_MODEL * SH_INTER / 4);
  // shared down (strided A over concat G-half): M=2048, N=2048, K=2816
  gemm6_kernel<1><<<16 * 16, 256, 0, stream>>>(GU_s, Wb, out, nullptr, nullptr,
                                               D_MODEL, SH_INTER, 2 * SH_INTER, 16, 16);

  // ---- routed experts ----
  cvt_bf16_kernel<<<8192, 256, 0, stream>>>(W1, Wb, 16 * N_INTER * D_MODEL / 4);
  gemm6_kernel<2><<<16 * 11 * 16, 256, 0, stream>>>(xbf, Wb, Gbuf, list, cnt,
                                                    N_INTER, D_MODEL, D_MODEL, 16, 11);
  cvt_bf16_kernel<<<8192, 256, 0, stream>>>(W3, Wb, 16 * N_INTER * D_MODEL / 4);
  gemm6_kernel<2><<<16 * 11 * 16, 256, 0, stream>>>(xbf, Wb, Ubuf, list, cnt,
                                                    N_INTER, D_MODEL, D_MODEL, 16, 11);
  swiglu2_kernel<<<2048, 256, 0, stream>>>(Gbuf, Ubuf, NSLOT * N_INTER / 8);
  cvt_bf16_kernel<<<8192, 256, 0, stream>>>(W2, Wb, 16 * D_MODEL * N_INTER / 4);
  gemm6_kernel<3><<<16 * 16 * 16, 256, 0, stream>>>(Gbuf, Wb, H2, list, cnt,
                                                    D_MODEL, N_INTER, N_INTER, 16, 16);
  combine_kernel<<<T_TOK, 256, 0, stream>>>(H2, wslot, out);
}